// Round 2
// baseline (205.779 us; speedup 1.0000x reference)
//
#include <hip/hip_runtime.h>
#include <hip/hip_bf16.h>
#include <stdint.h>

typedef __attribute__((ext_vector_type(8))) short  vshort8;
typedef __attribute__((ext_vector_type(4))) float  vfloat4;

static constexpr int Bb   = 8;
static constexpr int Nn   = 1024;
static constexpr int FIN  = 512;
static constexpr int FOUT = 512;
static constexpr int Hh   = 8;
static constexpr int DH   = 64;
static constexpr int Mm   = Bb * Nn;          // 8192
static constexpr float LRELU_ALPHA = 0.2f;

__device__ __forceinline__ unsigned short f2bf(float f) {
  union { float f; uint32_t u; } c; c.f = f;
  uint32_t r = c.u + 0x7fffu + ((c.u >> 16) & 1u);   // RNE
  return (unsigned short)(r >> 16);
}
__device__ __forceinline__ float bf2f(unsigned short s) {
  union { uint32_t u; float f; } c; c.u = ((uint32_t)s) << 16; return c.f;
}

// ---------------- K1: cast x -> bf16 (into d_out scratch) ----------------
__global__ __launch_bounds__(256) void cast_x_kernel(const float* __restrict__ x,
                                                     short* __restrict__ xb, int n) {
  int i = (blockIdx.x * 256 + threadIdx.x) * 8;
  const int stride = gridDim.x * 256 * 8;
  for (; i < n; i += stride) {
    vfloat4 v0 = *(const vfloat4*)(x + i);
    vfloat4 v1 = *(const vfloat4*)(x + i + 4);
    vshort8 o;
    o[0] = (short)f2bf(v0[0]); o[1] = (short)f2bf(v0[1]);
    o[2] = (short)f2bf(v0[2]); o[3] = (short)f2bf(v0[3]);
    o[4] = (short)f2bf(v1[0]); o[5] = (short)f2bf(v1[1]);
    o[6] = (short)f2bf(v1[2]); o[7] = (short)f2bf(v1[3]);
    *(vshort8*)(xb + i) = o;
  }
}

// ---------------- K1b: W[k][n] -> Wt[n][k] bf16 (into d_out scratch) ------
__global__ __launch_bounds__(256) void transpose_w_kernel(const float* __restrict__ W,
                                                          short* __restrict__ Wt) {
  __shared__ float tile[64 * 65];
  const int n0 = blockIdx.x * 64, k0 = blockIdx.y * 64;
  const int c = threadIdx.x & 63, r4 = threadIdx.x >> 6;
  #pragma unroll
  for (int rr = 0; rr < 64; rr += 4)
    tile[(rr + r4) * 65 + c] = W[(size_t)(k0 + rr + r4) * FOUT + n0 + c];
  __syncthreads();
  #pragma unroll
  for (int rr = 0; rr < 64; rr += 4)
    Wt[(size_t)(n0 + rr + r4) * FIN + k0 + c] = (short)f2bf(tile[c * 65 + rr + r4]);
}

// ---------------- K2: hbt[b,h,d,n] = (xb @ W + bias)^T via swapped MFMA ---
__global__ __launch_bounds__(256) void gemm_t_kernel(const short* __restrict__ A,
                                                     const short* __restrict__ Bt,
                                                     const float* __restrict__ bias,
                                                     short* __restrict__ hbt) {
  __shared__ short As[128 * 64];
  __shared__ short Bs[128 * 64];
  const int tid = threadIdx.x;
  const int w = tid >> 6, l = tid & 63;
  const int wv = w >> 1;   // fout half of block tile
  const int wu = w & 1;    // m half of block tile
  const int lrow = l & 15, lk = l >> 4;
  const int m0 = blockIdx.x * 128, n0 = blockIdx.y * 128;
  vfloat4 acc[4][4] = {};
  for (int kt = 0; kt < FIN; kt += 64) {
    #pragma unroll
    for (int itr = 0; itr < 4; ++itr) {
      const int e = w * 2048 + itr * 512 + l * 8;
      const int row = e >> 6, col = e & 63;
      __builtin_amdgcn_global_load_lds(
          (const __attribute__((address_space(1))) unsigned int*)(A + (size_t)(m0 + row) * FIN + kt + col),
          (__attribute__((address_space(3))) unsigned int*)(As + w * 2048 + itr * 512),
          16, 0, 0);
      __builtin_amdgcn_global_load_lds(
          (const __attribute__((address_space(1))) unsigned int*)(Bt + (size_t)(n0 + row) * FIN + kt + col),
          (__attribute__((address_space(3))) unsigned int*)(Bs + w * 2048 + itr * 512),
          16, 0, 0);
    }
    __syncthreads();
    #pragma unroll
    for (int ks = 0; ks < 2; ++ks) {
      vshort8 af[4], bfr[4];
      #pragma unroll
      for (int i = 0; i < 4; ++i)   // A-operand of MFMA = Wt rows (fout dim)
        af[i] = *(const vshort8*)(Bs + (wv * 64 + i * 16 + lrow) * 64 + ks * 32 + lk * 8);
      #pragma unroll
      for (int j = 0; j < 4; ++j)   // B-operand of MFMA = x rows (m dim)
        bfr[j] = *(const vshort8*)(As + (wu * 64 + j * 16 + lrow) * 64 + ks * 32 + lk * 8);
      #pragma unroll
      for (int i = 0; i < 4; ++i)
        #pragma unroll
        for (int j = 0; j < 4; ++j)
          acc[i][j] = __builtin_amdgcn_mfma_f32_16x16x32_bf16(af[i], bfr[j], acc[i][j], 0, 0, 0);
    }
    __syncthreads();
  }
  // D layout: row (lk*4+r) = fout-local, col (lrow) = m-local  -> direct hbt write
  #pragma unroll
  for (int i = 0; i < 4; ++i) {
    const int fbase = n0 + wv * 64 + i * 16 + lk * 4;
    const vfloat4 bv = *(const vfloat4*)(bias + fbase);
    #pragma unroll
    for (int r = 0; r < 4; ++r) {
      const int fg = fbase + r;
      const int h = fg >> 6, d = fg & 63;
      #pragma unroll
      for (int j = 0; j < 4; ++j) {
        const int mg = m0 + wu * 64 + j * 16 + lrow;
        const int b = mg >> 10, n = mg & 1023;
        hbt[((size_t)(b * Hh + h) * DH + d) * Nn + n] = (short)f2bf(acc[i][j][r] + bv[r]);
      }
    }
  }
}

// ---------------- K3: s_src/s_dst from hbt ----------------
__global__ __launch_bounds__(256) void scores_kernel(const short* __restrict__ hbt,
                                                     const float* __restrict__ att,
                                                     float* __restrict__ ssrc,
                                                     float* __restrict__ sdst) {
  const int bh = blockIdx.y;                 // b*8 + h
  const int h = bh & 7;
  const int n = blockIdx.x * 256 + threadIdx.x;
  const short* base = hbt + (size_t)bh * DH * Nn + n;
  const float* as_ = att + h * 2 * DH;
  const float* ad_ = as_ + DH;
  float ps = 0.f, pd = 0.f;
  #pragma unroll
  for (int d = 0; d < DH; ++d) {
    const float v = bf2f((unsigned short)base[(size_t)d * Nn]);
    ps += v * as_[d];
    pd += v * ad_[d];
  }
  ssrc[(size_t)bh * Nn + n] = ps;
  sdst[(size_t)bh * Nn + n] = pd;
}

// ---------------- K4: fused masked-softmax attention + PV + ELU ----------------
__global__ __launch_bounds__(256) void attn_kernel(const int* __restrict__ adj,
                                                   const float* __restrict__ ssrc,
                                                   const float* __restrict__ sdst,
                                                   const short* __restrict__ hbt,
                                                   float* __restrict__ out) {
  const int it = blockIdx.x, h = blockIdx.y, b = blockIdx.z;
  const int tid = threadIdx.x;
  const int w = tid >> 6, l = tid & 63;
  const int lrow = l & 15, lk = l >> 4;
  const int i = it * 64 + w * 16 + lrow;           // query row owned by this lane (A-frag row)
  const float sdi = sdst[(size_t)(b * Hh + h) * Nn + i];
  const float* ssp = ssrc + (size_t)(b * Hh + h) * Nn;
  const int* adjrow = adj + ((size_t)b * Nn + i) * Nn;
  const short* vb = hbt + (size_t)(b * Hh + h) * DH * Nn;
  vfloat4 acc[4] = {};
  float dsum = 0.f;
  for (int j0 = 0; j0 < Nn; j0 += 32) {
    const int jb = j0 + lk * 8;
    vfloat4 s0 = *(const vfloat4*)(ssp + jb);
    vfloat4 s1 = *(const vfloat4*)(ssp + jb + 4);
    const int4 a0 = *(const int4*)(adjrow + jb);
    const int4 a1 = *(const int4*)(adjrow + jb + 4);
    const float sv[8] = {s0[0], s0[1], s0[2], s0[3], s1[0], s1[1], s1[2], s1[3]};
    const int   av[8] = {a0.x, a0.y, a0.z, a0.w, a1.x, a1.y, a1.z, a1.w};
    vshort8 af;
    #pragma unroll
    for (int e = 0; e < 8; ++e) {
      float tv = sdi + sv[e];
      tv = fmaxf(tv, LRELU_ALPHA * tv);              // leaky_relu, alpha<1
      const float pe = (av[e] > 0) ? __expf(tv) : 0.f; // exp w/o max-sub: logits bounded ~9
      const unsigned short pb = f2bf(pe);
      af[e] = (short)pb;
      dsum += bf2f(pb);                              // denom consistent with bf16 numerator
    }
    vshort8 bfr[4];
    #pragma unroll
    for (int df = 0; df < 4; ++df)
      bfr[df] = *(const vshort8*)(vb + (size_t)(df * 16 + lrow) * Nn + jb);
    #pragma unroll
    for (int df = 0; df < 4; ++df)
      acc[df] = __builtin_amdgcn_mfma_f32_16x16x32_bf16(af, bfr[df], acc[df], 0, 0, 0);
  }
  dsum += __shfl_xor(dsum, 16);
  dsum += __shfl_xor(dsum, 32);
  #pragma unroll
  for (int r = 0; r < 4; ++r) {
    const int lr = lk * 4 + r;                       // local output row (C/D layout)
    const float den = __shfl(dsum, lr);
    const float inv = 1.0f / den;
    const int row = it * 64 + w * 16 + lr;
    #pragma unroll
    for (int df = 0; df < 4; ++df) {
      float v = acc[df][r] * inv;
      v = v > 0.f ? v : expm1f(v);                   // ELU (alpha=1)
      out[((size_t)(b * Nn + row)) * FOUT + h * DH + df * 16 + lrow] = v;
    }
  }
}

extern "C" void kernel_launch(void* const* d_in, const int* in_sizes, int n_in,
                              void* d_out, int out_size, void* d_ws, size_t ws_size,
                              hipStream_t stream) {
  const float* x   = (const float*)d_in[0];
  const int*   adj = (const int*)d_in[1];
  const float* W   = (const float*)d_in[2];
  const float* Wb  = (const float*)d_in[3];
  const float* att = (const float*)d_in[4];
  float* out = (float*)d_out;

  // Scratch plan:
  //   d_out (16 MB, fully overwritten by attn_kernel at the end):
  //     [0, 8 MB)   xb  = bf16 cast of x            (dead after gemm)
  //     [8, 8.5 MB) Wt  = bf16 W^T [fout][fin]      (dead after gemm)
  //   d_ws (8.5 MB used — stays well inside workspace):
  //     [0, 8 MB)   hbt = (x@W+b)^T as [b][h][d][n] bf16
  //     [8, 8.5 MB) ssrc, sdst (f32)
  short* xb  = (short*)d_out;
  short* Wt  = xb + (size_t)Mm * FIN;
  short* hbt = (short*)d_ws;
  float* ssrc = (float*)(hbt + (size_t)Bb * Hh * DH * Nn);
  float* sdst = ssrc + (size_t)Bb * Hh * Nn;

  cast_x_kernel<<<1024, 256, 0, stream>>>(x, xb, Mm * FIN);
  transpose_w_kernel<<<dim3(FOUT / 64, FIN / 64), 256, 0, stream>>>(W, Wt);
  gemm_t_kernel<<<dim3(Mm / 128, FOUT / 128), 256, 0, stream>>>(xb, Wt, Wb, hbt);
  scores_kernel<<<dim3(Nn / 256, Bb * Hh), 256, 0, stream>>>(hbt, att, ssrc, sdst);
  attn_kernel<<<dim3(Nn / 64, Hh, Bb), 256, 0, stream>>>(adj, ssrc, sdst, hbt, out);
}